// Round 4
// baseline (419.245 us; speedup 1.0000x reference)
//
#include <hip/hip_runtime.h>
#include <stdint.h>

#define DEVI static __device__ __forceinline__

typedef __attribute__((ext_vector_type(8))) short short8;
typedef __attribute__((ext_vector_type(4))) float floatx4;
typedef __attribute__((ext_vector_type(4))) unsigned short ushortx4;
typedef __attribute__((ext_vector_type(2))) long longx2;

// ---------- bf16 helpers ----------
DEVI unsigned short f2bf(float f) {
  union { float f; uint32_t u; } v; v.f = f;
  uint32_t r = v.u + 0x7FFFu + ((v.u >> 16) & 1u);
  return (unsigned short)(r >> 16);
}
DEVI unsigned short f2bf_trunc(float f) {
  union { float f; uint32_t u; } v; v.f = f;
  return (unsigned short)(v.u >> 16);
}
DEVI float bf2f(unsigned short s) {
  union { uint32_t u; float f; } v; v.u = ((uint32_t)s) << 16;
  return v.f;
}
DEVI uint32_t fbits(float f) {
  union { float f; uint32_t u; } v; v.f = f;
  return v.u;
}
// f32 -> fp8 e4m3 (OCP)
DEVI unsigned char f2fp8(float f) {
  return (unsigned char)(__builtin_amdgcn_cvt_pk_fp8_f32(f, f, 0, false) & 0xff);
}

// ---------- async global->LDS 16B ----------
DEVI void lds_cp16(void* lds, const void* g) {
  __builtin_amdgcn_global_load_lds(
      (const __attribute__((address_space(1))) uint32_t*)g,
      reinterpret_cast<__attribute__((address_space(3))) uint32_t*>(
          (uint32_t)reinterpret_cast<uintptr_t>(lds)),
      16, 0, 0);
}

// =====================================================================
// Convert: Q (first 8192 blocks) f32->bf16; K (next 16384 blocks) f32->fp8
// =====================================================================
__global__ __launch_bounds__(256) void cvt_qk(const float* __restrict__ Q,
                                              const float* __restrict__ K,
                                              unsigned short* __restrict__ Qb,
                                              unsigned char* __restrict__ Kf8) {
  const int bid = blockIdx.x;
  if (bid < 8192) {
    const size_t i = (size_t)bid * 256 + threadIdx.x;
    const floatx4 v = ((const floatx4*)Q)[i];
    ushortx4 o;
    o.x = f2bf(v.x); o.y = f2bf(v.y); o.z = f2bf(v.z); o.w = f2bf(v.w);
    ((ushortx4*)Qb)[i] = o;
  } else {
    const size_t i = (size_t)(bid - 8192) * 256 + threadIdx.x;
    const floatx4 v = ((const floatx4*)K)[i];
    int p = __builtin_amdgcn_cvt_pk_fp8_f32(v.x, v.y, 0, false);
    p = __builtin_amdgcn_cvt_pk_fp8_f32(v.z, v.w, p, true);
    ((int*)Kf8)[i] = p;
  }
}

// =====================================================================
// Weight transposes. z: 0=Wq(bf16), 1=Wk(fp8), 2=Wv(fp8), 3=Wo(bf16).
// =====================================================================
__global__ __launch_bounds__(256) void wtrans4(const float* __restrict__ Wq,
                                               const float* __restrict__ Wk,
                                               const float* __restrict__ Wv,
                                               const float* __restrict__ Wo,
                                               unsigned short* __restrict__ Wt,
                                               unsigned char* __restrict__ Wt8) {
  __shared__ float t[32][33];
  const int tx = threadIdx.x, ty = threadIdx.y;
  const int z = blockIdx.z;
  const float* W = (z == 0) ? Wq : (z == 1) ? Wk : (z == 2) ? Wv : Wo;
  const int c0 = blockIdx.x * 32, r0 = blockIdx.y * 32;
#pragma unroll
  for (int i = 0; i < 4; i++)
    t[ty + i * 8][tx] = W[(size_t)(r0 + ty + i * 8) * 1024 + c0 + tx];
  __syncthreads();
  if (z == 0 || z == 3) {
    unsigned short* D = Wt + (z == 0 ? 0 : (size_t)1024 * 1024);
#pragma unroll
    for (int i = 0; i < 4; i++)
      D[(size_t)(c0 + ty + i * 8) * 1024 + r0 + tx] = f2bf(t[tx][ty + i * 8]);
  } else {
    unsigned char* D = Wt8 + (z == 1 ? 0 : (size_t)1024 * 1024);
#pragma unroll
    for (int i = 0; i < 4; i++)
      D[(size_t)(c0 + ty + i * 8) * 1024 + r0 + tx] = f2fp8(t[tx][ty + i * 8]);
  }
}

// =====================================================================
// GEMM 128x128 tile bf16 (Q / Wo): C[8192][1024] = A @ Bt^T + bias
// XCD m-banded. EPI: 0 = bf16 out; 2 = bf16 fused O2 = X1 + relu(acc+bias)
// =====================================================================
template <int EPI>
__global__ __launch_bounds__(256, 3) void gemm_bt(
    const unsigned short* __restrict__ A, const unsigned short* __restrict__ Bt,
    const float* __restrict__ bias, const unsigned short* __restrict__ X1,
    void* __restrict__ Cout) {
  __shared__ unsigned short As[2][4][128][8];
  __shared__ unsigned short Bs[2][4][128][8];

  const int tid = threadIdx.x;
  const int lane = tid & 63, w = tid >> 6;
  const int wr = w >> 1, wc = w & 1;
  const int qd = lane >> 4, l16 = lane & 15;
  const int bid = blockIdx.x;
  const int xcd = bid & 7, loc = bid >> 3;
  const int m0 = (xcd * 8 + (loc & 7)) * 128;
  const int n0 = (loc >> 3) * 128;

  floatx4 acc[4][4];
#pragma unroll
  for (int i = 0; i < 4; i++)
#pragma unroll
    for (int j = 0; j < 4; j++) { floatx4 z = {0.f, 0.f, 0.f, 0.f}; acc[i][j] = z; }

  const int prow = tid & 127;
  const unsigned short* aptr = A + (size_t)(m0 + prow) * 1024 + ((tid >> 7) << 3);
  const unsigned short* bptr = Bt + (size_t)(n0 + prow) * 1024 + ((tid >> 7) << 3);
  const int dstoff = tid * 8;

  lds_cp16(&As[0][0][0][0] + dstoff, aptr);
  lds_cp16(&As[0][0][0][0] + dstoff + 2048, aptr + 16);
  lds_cp16(&Bs[0][0][0][0] + dstoff, bptr);
  lds_cp16(&Bs[0][0][0][0] + dstoff + 2048, bptr + 16);

  for (int it = 0; it < 32; it++) {
    __syncthreads();
    if (it < 31) {
      const int nb = (it + 1) & 1, k0 = (it + 1) * 32;
      lds_cp16(&As[nb][0][0][0] + dstoff, aptr + k0);
      lds_cp16(&As[nb][0][0][0] + dstoff + 2048, aptr + k0 + 16);
      lds_cp16(&Bs[nb][0][0][0] + dstoff, bptr + k0);
      lds_cp16(&Bs[nb][0][0][0] + dstoff + 2048, bptr + k0 + 16);
    }
    const int cur = it & 1;
    short8 af[4], bf[4];
#pragma unroll
    for (int mi = 0; mi < 4; mi++)
      af[mi] = *(const short8*)&As[cur][qd][wr * 64 + mi * 16 + l16][0];
#pragma unroll
    for (int ni = 0; ni < 4; ni++)
      bf[ni] = *(const short8*)&Bs[cur][qd][wc * 64 + ni * 16 + l16][0];
#pragma unroll
    for (int mi = 0; mi < 4; mi++)
#pragma unroll
      for (int ni = 0; ni < 4; ni++)
        acc[mi][ni] =
            __builtin_amdgcn_mfma_f32_16x16x32_bf16(af[mi], bf[ni], acc[mi][ni], 0, 0, 0);
  }

#pragma unroll
  for (int mi = 0; mi < 4; mi++) {
#pragma unroll
    for (int ni = 0; ni < 4; ni++) {
      const int row = m0 + wr * 64 + mi * 16 + qd * 4;
      const int col = n0 + wc * 64 + ni * 16 + l16;
      const float bv = bias[col];
      if constexpr (EPI == 0) {
        unsigned short* C = (unsigned short*)Cout;
#pragma unroll
        for (int r = 0; r < 4; r++)
          C[(size_t)(row + r) * 1024 + col] = f2bf(acc[mi][ni][r] + bv);
      } else {
        unsigned short* C = (unsigned short*)Cout;
#pragma unroll
        for (int r = 0; r < 4; r++) {
          const float x1 = bf2f(X1[(size_t)(row + r) * 1024 + col]);
          C[(size_t)(row + r) * 1024 + col] = f2bf(x1 + fmaxf(acc[mi][ni][r] + bv, 0.f));
        }
      }
    }
  }
}

// =====================================================================
// KV GEMM in FP8 e4m3: C[16384][2048] = Kf8 @ Wt8^T + bias
// Quad-buffered LDS (4 x 16KB), 3-K-steps-ahead prefetch, COUNTED vmcnt
// (steady state 12 loads in flight across raw s_barriers — no vmcnt(0)
// drain per K-step). Fragment reads: k-commutative b128 granule (lane qd
// reads chunk qd; conflict-free; A and B share the k-permutation).
// K half -> bf16 rowmajor (CK). V half -> fp8 kv-chunked for attn:
//   V8[(((b*8+h)*256 + nk/8)*128 + dh)*8 + (nk&7)]
// =====================================================================
__global__ __launch_bounds__(256, 2) void gemm_kv_f8(
    const unsigned char* __restrict__ A, const unsigned char* __restrict__ Bt,
    const float* __restrict__ biasK, const float* __restrict__ biasV,
    unsigned short* __restrict__ CK, unsigned char* __restrict__ CV8) {
  __shared__ unsigned char As[4][4][128][16];  // 32 KB: [buf][kchunk][row][16B]
  __shared__ unsigned char Bs[4][4][128][16];  // 32 KB

  const int tid = threadIdx.x;
  const int lane = tid & 63, w = tid >> 6;
  const int wr = w >> 1, wc = w & 1;
  const int qd = lane >> 4, l16 = lane & 15;
  const int bid = blockIdx.x;
  const int xcd = bid & 7, loc = bid >> 3;
  const int m0 = (xcd * 16 + (loc & 15)) * 128;
  const int n0 = (loc >> 4) * 128;

  floatx4 acc[4][4];
#pragma unroll
  for (int i = 0; i < 4; i++)
#pragma unroll
    for (int j = 0; j < 4; j++) { floatx4 z = {0.f, 0.f, 0.f, 0.f}; acc[i][j] = z; }

  const int srow = tid & 127, sc = tid >> 7;
  const unsigned char* aptr = A + (size_t)(m0 + srow) * 1024 + sc * 16;
  const unsigned char* bptr = Bt + (size_t)(n0 + srow) * 1024 + sc * 16;
  unsigned char* dA0 = &As[0][sc][srow][0];
  unsigned char* dB0 = &Bs[0][sc][srow][0];

#define KV_STAGE(step)                                   \
  {                                                      \
    const int buf_ = (step) & 3, k0_ = (step) * 64;      \
    lds_cp16(dA0 + buf_ * 8192, aptr + k0_);             \
    lds_cp16(dA0 + buf_ * 8192 + 4096, aptr + k0_ + 32); \
    lds_cp16(dB0 + buf_ * 8192, bptr + k0_);             \
    lds_cp16(dB0 + buf_ * 8192 + 4096, bptr + k0_ + 32); \
  }

  KV_STAGE(0);
  KV_STAGE(1);
  KV_STAGE(2);

  for (int it = 0; it < 16; it++) {
    if (it < 13) KV_STAGE(it + 3);
    // Wait only for step `it`'s 4 loads; keep younger steps in flight.
    if (it < 13)       asm volatile("s_waitcnt vmcnt(12)" ::: "memory");
    else if (it == 13) asm volatile("s_waitcnt vmcnt(8)" ::: "memory");
    else if (it == 14) asm volatile("s_waitcnt vmcnt(4)" ::: "memory");
    else               asm volatile("s_waitcnt vmcnt(0)" ::: "memory");
    __builtin_amdgcn_s_barrier();
    __builtin_amdgcn_sched_barrier(0);  // keep ds_reads below the barrier

    const int cur = it & 3;
    longx2 av[4], bvv[4];
#pragma unroll
    for (int mi = 0; mi < 4; mi++) {
      const int row = wr * 64 + mi * 16 + l16;
      av[mi] = *(const longx2*)&As[cur][qd][row][0];
    }
#pragma unroll
    for (int ni = 0; ni < 4; ni++) {
      const int row = wc * 64 + ni * 16 + l16;
      bvv[ni] = *(const longx2*)&Bs[cur][qd][row][0];
    }
#pragma unroll
    for (int mi = 0; mi < 4; mi++)
#pragma unroll
      for (int ni = 0; ni < 4; ni++)
        acc[mi][ni] = __builtin_amdgcn_mfma_f32_16x16x32_fp8_fp8(
            av[mi].x, bvv[ni].x, acc[mi][ni], 0, 0, 0);
#pragma unroll
    for (int mi = 0; mi < 4; mi++)
#pragma unroll
      for (int ni = 0; ni < 4; ni++)
        acc[mi][ni] = __builtin_amdgcn_mfma_f32_16x16x32_fp8_fp8(
            av[mi].y, bvv[ni].y, acc[mi][ni], 0, 0, 0);

    __builtin_amdgcn_sched_barrier(0);  // all LDS reads done before barrier2
    __builtin_amdgcn_s_barrier();       // protects buf (it+1)+3 overwrite
  }
#undef KV_STAGE

#pragma unroll
  for (int mi = 0; mi < 4; mi++) {
#pragma unroll
    for (int ni = 0; ni < 4; ni++) {
      const int row = m0 + wr * 64 + mi * 16 + qd * 4;
      const int col = n0 + wc * 64 + ni * 16 + l16;
      if (col < 1024) {
        const float bv = biasK[col];
#pragma unroll
        for (int r = 0; r < 4; r++)
          CK[(size_t)(row + r) * 1024 + col] = f2bf(acc[mi][ni][r] + bv);
      } else {
        const int vc = col - 1024;
        const float bv = biasV[vc];
        const int bb = row >> 11, nk = row & 2047;
        const int hh = vc >> 7, dh = vc & 127;
        // 4 consecutive kv (nk..nk+3) packed as fp8 into one u32; nk&7 in {0,4}
        int p = __builtin_amdgcn_cvt_pk_fp8_f32(acc[mi][ni][0] + bv,
                                                acc[mi][ni][1] + bv, 0, false);
        p = __builtin_amdgcn_cvt_pk_fp8_f32(acc[mi][ni][2] + bv,
                                            acc[mi][ni][3] + bv, p, true);
        *(uint32_t*)&CV8[((((size_t)(bb * 8 + hh)) * 256 + (nk >> 3)) * 128 + dh) * 8 +
                         (nk & 7)] = (uint32_t)p;
      }
    }
  }
}

// =====================================================================
// Flash attention v3 — transposed-S; QK^T bf16, PV in FP8. KVBLK=32
// (R2-proven structure, 84.3 us). S^T = K.Q^T; P packed to fp8 e4m3
// (4 kv / u32) -> 8 ds_bpermute/iter -> P^T B-frags; O^T = V^T.P^T with
// V staged fp8 (4 KB/tile, ds_read_b64 frags). LDS: K 2x8KB + V 2x4KB.
// s_setprio around MFMA clusters. 3 blk/CU bound.
// =====================================================================
__global__ __launch_bounds__(256, 3) void attn(
    const unsigned short* __restrict__ qb, const unsigned short* __restrict__ kb,
    const unsigned char* __restrict__ vt8, unsigned short* __restrict__ Ob) {
  __shared__ __align__(16) unsigned char smc[32768];
  unsigned short* sm16 = (unsigned short*)smc;

  const int tid = threadIdx.x;
  const int lane = tid & 63, w = tid >> 6;
  const int qd = lane >> 4, l16 = lane & 15;
  const int bid = blockIdx.x;
  const int qt = bid >> 6, bh = bid & 63;
  const int h = bh >> 3, b = bh & 7;
  const int m0 = qt * 128;

  const size_t qbase = ((size_t)(b * 1024 + m0)) * 1024 + h * 128;
  const size_t kbase = ((size_t)(b * 2048)) * 1024 + h * 128;
  const size_t vbase8 = (size_t)(b * 8 + h) * 262144;  // (b*8+h)*256*128*8 bytes

  // ---- stage Q transiently (all 32 KB), extract qf, release ----
#pragma unroll
  for (int i = 0; i < 8; i++) {
    const int p = i * 256 + tid;
    const int row = p & 127, c = p >> 7;
    lds_cp16(&sm16[c * 1024 + row * 8], qb + qbase + (size_t)row * 1024 + c * 8);
  }
  __syncthreads();
  short8 qf[2][4];  // [nt][ks]: B-frag rows q = w*32 + nt*16 + l16
#pragma unroll
  for (int nt = 0; nt < 2; nt++)
#pragma unroll
    for (int ks = 0; ks < 4; ks++)
      qf[nt][ks] =
          *(const short8*)&sm16[(ks * 4 + qd) * 1024 + (w * 32 + nt * 16 + l16) * 8];
  __syncthreads();

  // ---- stage KV tile 0 into buf 0 ----
  // K: bytes [0,16384): buf*8192 + kc*512 + kr*16   ([c16][kv32][16B])
  // V: bytes [16384,24576): 16384 + buf*4096 + vc*1024 + dh*8  ([vc4][dh128][8B])
#pragma unroll
  for (int i = 0; i < 2; i++) {
    const int p = i * 256 + tid;
    const int kr = p & 31, kc = p >> 5;
    lds_cp16(smc + kc * 512 + kr * 16, kb + kbase + (size_t)kr * 1024 + kc * 8);
  }
  {
    const int vc = tid >> 6, d2 = (tid & 63) * 2;
    lds_cp16(smc + 16384 + vc * 1024 + d2 * 8, vt8 + vbase8 + vc * 1024 + d2 * 8);
  }

  floatx4 oacc[8][2];  // O^T tiles [dh-tile][q-tile]
#pragma unroll
  for (int mt = 0; mt < 8; mt++)
#pragma unroll
    for (int nt = 0; nt < 2; nt++) { floatx4 z = {0.f, 0.f, 0.f, 0.f}; oacc[mt][nt] = z; }
  float lsum[2] = {0.f, 0.f};

  const int addrLo = ((qd & 1) * 32 + l16) * 4;  // src lane *4 for ds_bpermute
  const int addrHi = addrLo + 64;
  const bool loHalf = (lane < 32);

  for (int it = 0; it < 64; it++) {
    __syncthreads();
    if (it + 1 < 64) {
      const int nb = (it + 1) & 1, kv0 = (it + 1) * 32;
#pragma unroll
      for (int i = 0; i < 2; i++) {
        const int p = i * 256 + tid;
        const int kr = p & 31, kc = p >> 5;
        lds_cp16(smc + nb * 8192 + kc * 512 + kr * 16,
                 kb + kbase + (size_t)(kv0 + kr) * 1024 + kc * 8);
      }
      {
        const int vc = tid >> 6, d2 = (tid & 63) * 2;
        lds_cp16(smc + 16384 + nb * 4096 + vc * 1024 + d2 * 8,
                 vt8 + vbase8 + (size_t)kv0 * 128 + vc * 1024 + d2 * 8);
      }
    }
    const int cur = it & 1;

    // S^T = K Q^T  (wave: 32 kv rows x its 32 q cols)
    floatx4 st[2][2];  // [kv-tile mt][q-tile nt]
#pragma unroll
    for (int mt = 0; mt < 2; mt++)
#pragma unroll
      for (int nt = 0; nt < 2; nt++) { floatx4 z = {0.f, 0.f, 0.f, 0.f}; st[mt][nt] = z; }
    __builtin_amdgcn_s_setprio(1);
#pragma unroll
    for (int ks = 0; ks < 4; ks++) {
      const short8 ka =
          *(const short8*)(smc + cur * 8192 + (ks * 4 + qd) * 512 + l16 * 16);
      const short8 kb2 =
          *(const short8*)(smc + cur * 8192 + (ks * 4 + qd) * 512 + (16 + l16) * 16);
#pragma unroll
      for (int nt = 0; nt < 2; nt++) {
        st[0][nt] = __builtin_amdgcn_mfma_f32_16x16x32_bf16(ka, qf[nt][ks], st[0][nt], 0, 0, 0);
        st[1][nt] = __builtin_amdgcn_mfma_f32_16x16x32_bf16(kb2, qf[nt][ks], st[1][nt], 0, 0, 0);
      }
    }
    __builtin_amdgcn_s_setprio(0);

    // hoist V^T A-frags (fp8, 8B each) — latency hides under the exp VALU
    long vl[8];
#pragma unroll
    for (int mt = 0; mt < 8; mt++)
      vl[mt] = *(const long*)(smc + 16384 + cur * 4096 + qd * 1024 + (mt * 16 + l16) * 8);

    // P = exp(S^T/32): pack 4 fp8 per u32 (one kv-quad), per-lane row-sums
    uint32_t pkf[2][2];
#pragma unroll
    for (int mt = 0; mt < 2; mt++)
#pragma unroll
      for (int nt = 0; nt < 2; nt++) {
        const float e0 = __expf(st[mt][nt][0] * 0.03125f);
        const float e1 = __expf(st[mt][nt][1] * 0.03125f);
        const float e2 = __expf(st[mt][nt][2] * 0.03125f);
        const float e3 = __expf(st[mt][nt][3] * 0.03125f);
        lsum[nt] += (e0 + e1) + (e2 + e3);
        int p = __builtin_amdgcn_cvt_pk_fp8_f32(e0, e1, 0, false);
        p = __builtin_amdgcn_cvt_pk_fp8_f32(e2, e3, p, true);
        pkf[mt][nt] = (uint32_t)p;
      }

    // Assemble P^T fp8 B-frags via quad redistribution (4 bpermute/nt),
    // then O^T += V^T P^T in fp8
#pragma unroll
    for (int nt = 0; nt < 2; nt++) {
      int lo0 = __builtin_amdgcn_ds_bpermute(addrLo, (int)pkf[0][nt]);
      int lo1 = __builtin_amdgcn_ds_bpermute(addrLo, (int)pkf[1][nt]);
      int hi0 = __builtin_amdgcn_ds_bpermute(addrHi, (int)pkf[0][nt]);
      int hi1 = __builtin_amdgcn_ds_bpermute(addrHi, (int)pkf[1][nt]);
      union { int i[2]; long l; } u;
      u.i[0] = loHalf ? lo0 : lo1;
      u.i[1] = loHalf ? hi0 : hi1;
      const long pfl = u.l;
      __builtin_amdgcn_s_setprio(1);
#pragma unroll
      for (int mt = 0; mt < 8; mt++)
        oacc[mt][nt] =
            __builtin_amdgcn_mfma_f32_16x16x32_fp8_fp8(vl[mt], pfl, oacc[mt][nt], 0, 0, 0);
      __builtin_amdgcn_s_setprio(0);
    }
  }

  // finalize row sums (reduce over quads; q lives in l16)
  float inv[2];
#pragma unroll
  for (int nt = 0; nt < 2; nt++) {
    float s = lsum[nt];
    s += __shfl_xor(s, 16);
    s += __shfl_xor(s, 32);
    inv[nt] = 1.f / s;
  }

  // ---- transpose O^T back via XOR-swizzled LDS, add residual, store ----
  __syncthreads();  // all K/V reads done; smem reusable
#pragma unroll
  for (int mt = 0; mt < 8; mt++)
#pragma unroll
    for (int nt = 0; nt < 2; nt++) {
      const int q = w * 32 + nt * 16 + l16;
#pragma unroll
      for (int r = 0; r < 4; r++) {
        const int dh = mt * 16 + qd * 4 + r;
        const int c = dh >> 3, off = dh & 7;
        sm16[q * 128 + ((c ^ (q & 15)) * 8) + off] = f2bf_trunc(oacc[mt][nt][r] * inv[nt]);
      }
    }
  __syncthreads();
#pragma unroll
  for (int i = 0; i < 8; i++) {
    const int p = i * 256 + tid;
    const int row = p >> 4, c = p & 15;
    const short8 ov = *(const short8*)&sm16[row * 128 + ((c ^ (row & 15)) * 8)];
    const short8 qres = *(const short8*)(qb + qbase + (size_t)row * 1024 + c * 8);
    union { unsigned short us[8]; short8 s; } o;
#pragma unroll
    for (int e = 0; e < 8; e++)
      o.us[e] = f2bf(bf2f((unsigned short)ov[e]) + bf2f((unsigned short)qres[e]));
    *(short8*)(Ob + qbase + (size_t)row * 1024 + c * 8) = o.s;
  }
}

// =====================================================================
// Row LayerNorm over 1024 (bf16 -> bf16)
// =====================================================================
__global__ __launch_bounds__(256) void ln_rows(const unsigned short* __restrict__ X,
                                               const float* __restrict__ g,
                                               const float* __restrict__ bb,
                                               unsigned short* __restrict__ Y) {
  __shared__ float red[8];
  const int row = blockIdx.x, tid = threadIdx.x;
  const int w = tid >> 6, lane = tid & 63;
  const ushortx4 u = ((const ushortx4*)(X + (size_t)row * 1024))[tid];
  float x0 = bf2f(u.x), x1 = bf2f(u.y), x2 = bf2f(u.z), x3 = bf2f(u.w);
  float s = x0 + x1 + x2 + x3;
  float s2 = x0 * x0 + x1 * x1 + x2 * x2 + x3 * x3;
#pragma unroll
  for (int off = 1; off < 64; off <<= 1) { s += __shfl_xor(s, off); s2 += __shfl_xor(s2, off); }
  if (lane == 0) { red[w] = s; red[4 + w] = s2; }
  __syncthreads();
  s = red[0] + red[1] + red[2] + red[3];
  s2 = red[4] + red[5] + red[6] + red[7];
  const float mu = s * (1.f / 1024.f);
  const float rs = rsqrtf(s2 * (1.f / 1024.f) - mu * mu + 1e-5f);
  const floatx4 gv = ((const floatx4*)g)[tid];
  const floatx4 bv = ((const floatx4*)bb)[tid];
  ushortx4 o;
  o.x = f2bf((x0 - mu) * rs * gv.x + bv.x);
  o.y = f2bf((x1 - mu) * rs * gv.y + bv.y);
  o.z = f2bf((x2 - mu) * rs * gv.z + bv.z);
  o.w = f2bf((x3 - mu) * rs * gv.w + bv.w);
  ((ushortx4*)(Y + (size_t)row * 1024))[tid] = o;
}

// =====================================================================
// Row LayerNorm over 1024 (bf16 -> f32) for the final output
// =====================================================================
__global__ __launch_bounds__(256) void ln_b2f(const unsigned short* __restrict__ X,
                                              const float* __restrict__ g,
                                              const float* __restrict__ bb,
                                              float* __restrict__ out) {
  __shared__ float red[8];
  const int row = blockIdx.x, tid = threadIdx.x;
  const int w = tid >> 6, lane = tid & 63;
  const ushortx4 u = ((const ushortx4*)(X + (size_t)row * 1024))[tid];
  float x0 = bf2f(u.x), x1 = bf2f(u.y), x2 = bf2f(u.z), x3 = bf2f(u.w);
  float s = x0 + x1 + x2 + x3;
  float s2 = x0 * x0 + x1 * x1 + x2 * x2 + x3 * x3;
#pragma unroll
  for (int off = 1; off < 64; off <<= 1) { s += __shfl_xor(s, off); s2 += __shfl_xor(s2, off); }
  if (lane == 0) { red[w] = s; red[4 + w] = s2; }
  __syncthreads();
  s = red[0] + red[1] + red[2] + red[3];
  s2 = red[4] + red[5] + red[6] + red[7];
  const float mu = s * (1.f / 1024.f);
  const float rs = rsqrtf(s2 * (1.f / 1024.f) - mu * mu + 1e-5f);
  const floatx4 gv = ((const floatx4*)g)[tid];
  const floatx4 bv = ((const floatx4*)bb)[tid];
  floatx4 o;
  o.x = (x0 - mu) * rs * gv.x + bv.x;
  o.y = (x1 - mu) * rs * gv.y + bv.y;
  o.z = (x2 - mu) * rs * gv.z + bv.z;
  o.w = (x3 - mu) * rs * gv.w + bv.w;
  ((floatx4*)(out + (size_t)row * 1024))[tid] = o;
}

// =====================================================================
// Host launch
// =====================================================================
extern "C" void kernel_launch(void* const* d_in, const int* in_sizes, int n_in,
                              void* d_out, int out_size, void* d_ws, size_t ws_size,
                              hipStream_t stream) {
  (void)in_sizes; (void)n_in; (void)out_size; (void)ws_size;
  const float* Q  = (const float*)d_in[0];
  const float* K  = (const float*)d_in[1];
  const float* Wq = (const float*)d_in[2];
  const float* bq = (const float*)d_in[3];
  const float* Wk = (const float*)d_in[4];
  const float* bk = (const float*)d_in[5];
  const float* Wv = (const float*)d_in[6];
  const float* bv = (const float*)d_in[7];
  const float* Wo = (const float*)d_in[8];
  const float* bo = (const float*)d_in[9];
  const float* g0 = (const float*)d_in[10];
  const float* b0 = (const float*)d_in[11];
  const float* g1 = (const float*)d_in[12];
  const float* b1 = (const float*)d_in[13];
  float* out = (float*)d_out;

  char* ws = (char*)d_ws;
  const size_t MB = 1u << 20;
  unsigned short* Qb  = (unsigned short*)(ws + 0);         // 16 MB [later: O bf16]
  unsigned short* X1  = (unsigned short*)(ws + 16 * MB);   // 16 MB
  unsigned short* Wt  = (unsigned short*)(ws + 32 * MB);   // 4 MB bf16 [Wq^T;Wo^T]
  unsigned char*  Wt8 = (unsigned char*)(ws + 36 * MB);    // 2 MB fp8 [Wk^T;Wv^T]
  unsigned char*  Kf8 = (unsigned char*)(ws + 38 * MB);    // 16 MB
  unsigned short* qbp = (unsigned short*)(ws + 54 * MB);   // 16 MB
  unsigned short* kbp = (unsigned short*)(ws + 70 * MB);   // 32 MB [later: O2 bf16]
  unsigned char*  vt8 = (unsigned char*)(ws + 102 * MB);   // 16 MB fp8 V
  unsigned short* O   = Qb;
  unsigned short* O2b = (unsigned short*)(ws + 70 * MB);

  unsigned short* Wqt = Wt;
  unsigned short* Wot = Wt + (size_t)1024 * 1024;

  cvt_qk<<<24576, 256, 0, stream>>>(Q, K, Qb, Kf8);
  wtrans4<<<dim3(32, 32, 4), dim3(32, 8), 0, stream>>>(Wq, Wk, Wv, Wo, Wt, Wt8);

  // Q projection -> qbp (bf16 rowmajor), 128x128 bf16, XCD m-banded
  gemm_bt<0><<<512, 256, 0, stream>>>(Qb, Wqt, bq, nullptr, qbp);
  // fused K+V projection in FP8 (M=16384, N=2048); quad-buffered counted vmcnt
  gemm_kv_f8<<<2048, 256, 0, stream>>>(Kf8, Wt8, bk, bv, kbp, vt8);
  // attention (+ q residual) -> O bf16; QK bf16, PV fp8, KVBLK=32 (R2 struct)
  attn<<<512, 256, 0, stream>>>(qbp, kbp, vt8, O);
  // LN0
  ln_rows<<<8192, 256, 0, stream>>>(O, g0, b0, X1);
  // O2 = bf16(X1 + relu(X1 @ Wo + bo)), XCD m-banded
  gemm_bt<2><<<512, 256, 0, stream>>>(X1, Wot, bo, X1, O2b);
  // out = LN(O2)
  ln_b2f<<<8192, 256, 0, stream>>>(O2b, g1, b1, out);
}

// Round 6
// 407.880 us; speedup vs baseline: 1.0279x; 1.0279x over previous
//
#include <hip/hip_runtime.h>
#include <stdint.h>

#define DEVI static __device__ __forceinline__

typedef __attribute__((ext_vector_type(8))) short short8;
typedef __attribute__((ext_vector_type(4))) float floatx4;
typedef __attribute__((ext_vector_type(4))) unsigned short ushortx4;
typedef __attribute__((ext_vector_type(2))) long longx2;

// ---------- bf16 helpers ----------
DEVI unsigned short f2bf(float f) {
  union { float f; uint32_t u; } v; v.f = f;
  uint32_t r = v.u + 0x7FFFu + ((v.u >> 16) & 1u);
  return (unsigned short)(r >> 16);
}
DEVI unsigned short f2bf_trunc(float f) {
  union { float f; uint32_t u; } v; v.f = f;
  return (unsigned short)(v.u >> 16);
}
DEVI float bf2f(unsigned short s) {
  union { uint32_t u; float f; } v; v.u = ((uint32_t)s) << 16;
  return v.f;
}
DEVI uint32_t fbits(float f) {
  union { float f; uint32_t u; } v; v.f = f;
  return v.u;
}
// f32 -> fp8 e4m3 (OCP)
DEVI unsigned char f2fp8(float f) {
  return (unsigned char)(__builtin_amdgcn_cvt_pk_fp8_f32(f, f, 0, false) & 0xff);
}
// 8 bf16 -> 8 fp8 packed in a long
DEVI long pack8fp8(const short8 s) {
  int a = __builtin_amdgcn_cvt_pk_fp8_f32(bf2f((unsigned short)s[0]),
                                          bf2f((unsigned short)s[1]), 0, false);
  a = __builtin_amdgcn_cvt_pk_fp8_f32(bf2f((unsigned short)s[2]),
                                      bf2f((unsigned short)s[3]), a, true);
  int b = __builtin_amdgcn_cvt_pk_fp8_f32(bf2f((unsigned short)s[4]),
                                          bf2f((unsigned short)s[5]), 0, false);
  b = __builtin_amdgcn_cvt_pk_fp8_f32(bf2f((unsigned short)s[6]),
                                      bf2f((unsigned short)s[7]), b, true);
  union { int i[2]; long l; } u;
  u.i[0] = a; u.i[1] = b;
  return u.l;
}

// ---------- async global->LDS 16B ----------
DEVI void lds_cp16(void* lds, const void* g) {
  __builtin_amdgcn_global_load_lds(
      (const __attribute__((address_space(1))) uint32_t*)g,
      reinterpret_cast<__attribute__((address_space(3))) uint32_t*>(
          (uint32_t)reinterpret_cast<uintptr_t>(lds)),
      16, 0, 0);
}

// =====================================================================
// Convert: Q (first 8192 blocks) f32->bf16; K (next 16384 blocks) f32->fp8
// =====================================================================
__global__ __launch_bounds__(256) void cvt_qk(const float* __restrict__ Q,
                                              const float* __restrict__ K,
                                              unsigned short* __restrict__ Qb,
                                              unsigned char* __restrict__ Kf8) {
  const int bid = blockIdx.x;
  if (bid < 8192) {
    const size_t i = (size_t)bid * 256 + threadIdx.x;
    const floatx4 v = ((const floatx4*)Q)[i];
    ushortx4 o;
    o.x = f2bf(v.x); o.y = f2bf(v.y); o.z = f2bf(v.z); o.w = f2bf(v.w);
    ((ushortx4*)Qb)[i] = o;
  } else {
    const size_t i = (size_t)(bid - 8192) * 256 + threadIdx.x;
    const floatx4 v = ((const floatx4*)K)[i];
    int p = __builtin_amdgcn_cvt_pk_fp8_f32(v.x, v.y, 0, false);
    p = __builtin_amdgcn_cvt_pk_fp8_f32(v.z, v.w, p, true);
    ((int*)Kf8)[i] = p;
  }
}

// =====================================================================
// Weight transposes. z: 0=Wq(bf16), 1=Wk(fp8), 2=Wv(fp8), 3=Wo(bf16).
// =====================================================================
__global__ __launch_bounds__(256) void wtrans4(const float* __restrict__ Wq,
                                               const float* __restrict__ Wk,
                                               const float* __restrict__ Wv,
                                               const float* __restrict__ Wo,
                                               unsigned short* __restrict__ Wt,
                                               unsigned char* __restrict__ Wt8) {
  __shared__ float t[32][33];
  const int tx = threadIdx.x, ty = threadIdx.y;
  const int z = blockIdx.z;
  const float* W = (z == 0) ? Wq : (z == 1) ? Wk : (z == 2) ? Wv : Wo;
  const int c0 = blockIdx.x * 32, r0 = blockIdx.y * 32;
#pragma unroll
  for (int i = 0; i < 4; i++)
    t[ty + i * 8][tx] = W[(size_t)(r0 + ty + i * 8) * 1024 + c0 + tx];
  __syncthreads();
  if (z == 0 || z == 3) {
    unsigned short* D = Wt + (z == 0 ? 0 : (size_t)1024 * 1024);
#pragma unroll
    for (int i = 0; i < 4; i++)
      D[(size_t)(c0 + ty + i * 8) * 1024 + r0 + tx] = f2bf(t[tx][ty + i * 8]);
  } else {
    unsigned char* D = Wt8 + (z == 1 ? 0 : (size_t)1024 * 1024);
#pragma unroll
    for (int i = 0; i < 4; i++)
      D[(size_t)(c0 + ty + i * 8) * 1024 + r0 + tx] = f2fp8(t[tx][ty + i * 8]);
  }
}

// =====================================================================
// GEMM 128x128 tile bf16 (Q / Wo): C[8192][1024] = A @ Bt^T + bias
// XCD m-banded. EPI: 0 = bf16 out; 2 = bf16 fused O2 = X1 + relu(acc+bias)
// =====================================================================
template <int EPI>
__global__ __launch_bounds__(256, 3) void gemm_bt(
    const unsigned short* __restrict__ A, const unsigned short* __restrict__ Bt,
    const float* __restrict__ bias, const unsigned short* __restrict__ X1,
    void* __restrict__ Cout) {
  __shared__ unsigned short As[2][4][128][8];
  __shared__ unsigned short Bs[2][4][128][8];

  const int tid = threadIdx.x;
  const int lane = tid & 63, w = tid >> 6;
  const int wr = w >> 1, wc = w & 1;
  const int qd = lane >> 4, l16 = lane & 15;
  const int bid = blockIdx.x;
  const int xcd = bid & 7, loc = bid >> 3;
  const int m0 = (xcd * 8 + (loc & 7)) * 128;
  const int n0 = (loc >> 3) * 128;

  floatx4 acc[4][4];
#pragma unroll
  for (int i = 0; i < 4; i++)
#pragma unroll
    for (int j = 0; j < 4; j++) { floatx4 z = {0.f, 0.f, 0.f, 0.f}; acc[i][j] = z; }

  const int prow = tid & 127;
  const unsigned short* aptr = A + (size_t)(m0 + prow) * 1024 + ((tid >> 7) << 3);
  const unsigned short* bptr = Bt + (size_t)(n0 + prow) * 1024 + ((tid >> 7) << 3);
  const int dstoff = tid * 8;

  lds_cp16(&As[0][0][0][0] + dstoff, aptr);
  lds_cp16(&As[0][0][0][0] + dstoff + 2048, aptr + 16);
  lds_cp16(&Bs[0][0][0][0] + dstoff, bptr);
  lds_cp16(&Bs[0][0][0][0] + dstoff + 2048, bptr + 16);

  for (int it = 0; it < 32; it++) {
    __syncthreads();
    if (it < 31) {
      const int nb = (it + 1) & 1, k0 = (it + 1) * 32;
      lds_cp16(&As[nb][0][0][0] + dstoff, aptr + k0);
      lds_cp16(&As[nb][0][0][0] + dstoff + 2048, aptr + k0 + 16);
      lds_cp16(&Bs[nb][0][0][0] + dstoff, bptr + k0);
      lds_cp16(&Bs[nb][0][0][0] + dstoff + 2048, bptr + k0 + 16);
    }
    const int cur = it & 1;
    short8 af[4], bf[4];
#pragma unroll
    for (int mi = 0; mi < 4; mi++)
      af[mi] = *(const short8*)&As[cur][qd][wr * 64 + mi * 16 + l16][0];
#pragma unroll
    for (int ni = 0; ni < 4; ni++)
      bf[ni] = *(const short8*)&Bs[cur][qd][wc * 64 + ni * 16 + l16][0];
#pragma unroll
    for (int mi = 0; mi < 4; mi++)
#pragma unroll
      for (int ni = 0; ni < 4; ni++)
        acc[mi][ni] =
            __builtin_amdgcn_mfma_f32_16x16x32_bf16(af[mi], bf[ni], acc[mi][ni], 0, 0, 0);
  }

#pragma unroll
  for (int mi = 0; mi < 4; mi++) {
#pragma unroll
    for (int ni = 0; ni < 4; ni++) {
      const int row = m0 + wr * 64 + mi * 16 + qd * 4;
      const int col = n0 + wc * 64 + ni * 16 + l16;
      const float bv = bias[col];
      if constexpr (EPI == 0) {
        unsigned short* C = (unsigned short*)Cout;
#pragma unroll
        for (int r = 0; r < 4; r++)
          C[(size_t)(row + r) * 1024 + col] = f2bf(acc[mi][ni][r] + bv);
      } else {
        unsigned short* C = (unsigned short*)Cout;
#pragma unroll
        for (int r = 0; r < 4; r++) {
          const float x1 = bf2f(X1[(size_t)(row + r) * 1024 + col]);
          C[(size_t)(row + r) * 1024 + col] = f2bf(x1 + fmaxf(acc[mi][ni][r] + bv, 0.f));
        }
      }
    }
  }
}

// =====================================================================
// KV GEMM in FP8 e4m3: C[16384][2048] = Kf8 @ Wt8^T + bias
// 2-buffer __syncthreads loop (R3-proven). Fragment reads: k-commutative
// b128 granule (lane qd reads chunk qd; conflict-free; A and B share the
// k-permutation). K half -> FP8 rowmajor (CK8, attn reads fp8 K now).
// V half -> fp8 kv-chunked for attn:
//   V8[(((b*8+h)*256 + nk/8)*128 + dh)*8 + (nk&7)]
// =====================================================================
__global__ __launch_bounds__(256, 3) void gemm_kv_f8(
    const unsigned char* __restrict__ A, const unsigned char* __restrict__ Bt,
    const float* __restrict__ biasK, const float* __restrict__ biasV,
    unsigned char* __restrict__ CK8, unsigned char* __restrict__ CV8) {
  __shared__ unsigned char As[2][4][128][16];
  __shared__ unsigned char Bs[2][4][128][16];

  const int tid = threadIdx.x;
  const int lane = tid & 63, w = tid >> 6;
  const int wr = w >> 1, wc = w & 1;
  const int qd = lane >> 4, l16 = lane & 15;
  const int bid = blockIdx.x;
  const int xcd = bid & 7, loc = bid >> 3;
  const int m0 = (xcd * 16 + (loc & 15)) * 128;
  const int n0 = (loc >> 4) * 128;

  floatx4 acc[4][4];
#pragma unroll
  for (int i = 0; i < 4; i++)
#pragma unroll
    for (int j = 0; j < 4; j++) { floatx4 z = {0.f, 0.f, 0.f, 0.f}; acc[i][j] = z; }

  const int srow = tid & 127, sc = tid >> 7;
  const unsigned char* aptr = A + (size_t)(m0 + srow) * 1024 + sc * 16;
  const unsigned char* bptr = Bt + (size_t)(n0 + srow) * 1024 + sc * 16;
  unsigned char* dA = &As[0][sc][srow][0];
  unsigned char* dB = &Bs[0][sc][srow][0];

  lds_cp16(dA, aptr);
  lds_cp16(dA + 4096, aptr + 32);
  lds_cp16(dB, bptr);
  lds_cp16(dB + 4096, bptr + 32);

  for (int it = 0; it < 16; it++) {
    __syncthreads();
    if (it < 15) {
      const int nb = (it + 1) & 1, k0 = (it + 1) * 64;
      lds_cp16(dA + nb * 8192, aptr + k0);
      lds_cp16(dA + nb * 8192 + 4096, aptr + k0 + 32);
      lds_cp16(dB + nb * 8192, bptr + k0);
      lds_cp16(dB + nb * 8192 + 4096, bptr + k0 + 32);
    }
    const int cur = it & 1;
    longx2 av[4], bvv[4];
#pragma unroll
    for (int mi = 0; mi < 4; mi++) {
      const int row = wr * 64 + mi * 16 + l16;
      av[mi] = *(const longx2*)&As[cur][qd][row][0];
    }
#pragma unroll
    for (int ni = 0; ni < 4; ni++) {
      const int row = wc * 64 + ni * 16 + l16;
      bvv[ni] = *(const longx2*)&Bs[cur][qd][row][0];
    }
#pragma unroll
    for (int mi = 0; mi < 4; mi++)
#pragma unroll
      for (int ni = 0; ni < 4; ni++)
        acc[mi][ni] = __builtin_amdgcn_mfma_f32_16x16x32_fp8_fp8(
            av[mi].x, bvv[ni].x, acc[mi][ni], 0, 0, 0);
#pragma unroll
    for (int mi = 0; mi < 4; mi++)
#pragma unroll
      for (int ni = 0; ni < 4; ni++)
        acc[mi][ni] = __builtin_amdgcn_mfma_f32_16x16x32_fp8_fp8(
            av[mi].y, bvv[ni].y, acc[mi][ni], 0, 0, 0);
  }

#pragma unroll
  for (int mi = 0; mi < 4; mi++) {
#pragma unroll
    for (int ni = 0; ni < 4; ni++) {
      const int row = m0 + wr * 64 + mi * 16 + qd * 4;
      const int col = n0 + wc * 64 + ni * 16 + l16;
      if (col < 1024) {
        const float bv = biasK[col];
#pragma unroll
        for (int r = 0; r < 4; r++)
          CK8[(size_t)(row + r) * 1024 + col] = f2fp8(acc[mi][ni][r] + bv);
      } else {
        const int vc = col - 1024;
        const float bv = biasV[vc];
        const int bb = row >> 11, nk = row & 2047;
        const int hh = vc >> 7, dh = vc & 127;
        // 4 consecutive kv (nk..nk+3) packed as fp8 into one u32; nk&7 in {0,4}
        int p = __builtin_amdgcn_cvt_pk_fp8_f32(acc[mi][ni][0] + bv,
                                                acc[mi][ni][1] + bv, 0, false);
        p = __builtin_amdgcn_cvt_pk_fp8_f32(acc[mi][ni][2] + bv,
                                            acc[mi][ni][3] + bv, p, true);
        *(uint32_t*)&CV8[((((size_t)(bb * 8 + hh)) * 256 + (nk >> 3)) * 128 + dh) * 8 +
                         (nk & 7)] = (uint32_t)p;
      }
    }
  }
}

// =====================================================================
// Flash attention v4 — transposed-S; QK^T AND PV in FP8. KVBLK=32.
// K staged as 4 KB row-major fp8 with XOR-swizzled source granules
// (slot = chunk ^ (row&7)) so the in-loop k-commutative b128 granule read
// is bank-conflict-free. Q-frags converted once to granule-ordered fp8
// (k = qd*8+j intra-MFMA; global d = p*64 + qd*16 + j for .x, +8 for .y —
// identical permutation on A and B, contraction unchanged).
// LDS 16 KB live: K 2x4KB [kv32][slot8^][16B] + V 2x4KB [vc4][dh128][8B];
// 32 KB block for Q-stage/epilogue. s_setprio around MFMA clusters.
// =====================================================================
__global__ __launch_bounds__(256, 3) void attn(
    const unsigned short* __restrict__ qb, const unsigned char* __restrict__ kb8,
    const unsigned char* __restrict__ vt8, unsigned short* __restrict__ Ob) {
  __shared__ __align__(16) unsigned char smc[32768];
  unsigned short* sm16 = (unsigned short*)smc;

  const int tid = threadIdx.x;
  const int lane = tid & 63, w = tid >> 6;
  const int qd = lane >> 4, l16 = lane & 15;
  const int bid = blockIdx.x;
  const int qt = bid >> 6, bh = bid & 63;
  const int h = bh >> 3, b = bh & 7;
  const int m0 = qt * 128;

  const size_t qbase = ((size_t)(b * 1024 + m0)) * 1024 + h * 128;   // shorts
  const size_t kbase8 = ((size_t)(b * 2048)) * 1024 + h * 128;       // bytes
  const size_t vbase8 = (size_t)(b * 8 + h) * 262144;                // bytes

  // ---- stage Q transiently (all 32 KB bf16), build fp8 granule frags ----
#pragma unroll
  for (int i = 0; i < 8; i++) {
    const int p = i * 256 + tid;
    const int row = p & 127, c = p >> 7;
    lds_cp16(&sm16[c * 1024 + row * 8], qb + qbase + (size_t)row * 1024 + c * 8);
  }
  __syncthreads();
  // qx[p][nt] covers d = p*64 + qd*16 + (0..7); qy: +8..15  (granule order)
  long qx[2][2], qy[2][2];
#pragma unroll
  for (int p = 0; p < 2; p++)
#pragma unroll
    for (int nt = 0; nt < 2; nt++) {
      const int row = w * 32 + nt * 16 + l16;
      const short8 qa = *(const short8*)&sm16[(p * 8 + qd * 2) * 1024 + row * 8];
      const short8 qc = *(const short8*)&sm16[(p * 8 + qd * 2 + 1) * 1024 + row * 8];
      qx[p][nt] = pack8fp8(qa);
      qy[p][nt] = pack8fp8(qc);
    }
  __syncthreads();

  // ---- stage KV tile 0 into buf 0 ----
  // K: [0,8192): buf*4096 + kr*128 + slot*16, slot holds global chunk slot^(kr&7)
  // V: [8192,16384): 8192 + buf*4096 + vc*1024 + dh*8
  {
    const int kr = tid >> 3, sl = tid & 7;
    lds_cp16(smc + tid * 16,
             kb8 + kbase8 + (size_t)kr * 1024 + (sl ^ (kr & 7)) * 16);
    lds_cp16(smc + 8192 + tid * 16,
             vt8 + vbase8 + (size_t)(tid >> 6) * 1024 + (tid & 63) * 16);
  }

  floatx4 oacc[8][2];  // O^T tiles [dh-tile][q-tile]
#pragma unroll
  for (int mt = 0; mt < 8; mt++)
#pragma unroll
    for (int nt = 0; nt < 2; nt++) { floatx4 z = {0.f, 0.f, 0.f, 0.f}; oacc[mt][nt] = z; }
  float lsum[2] = {0.f, 0.f};

  const int addrLo = ((qd & 1) * 32 + l16) * 4;  // src lane *4 for ds_bpermute
  const int addrHi = addrLo + 64;
  const bool loHalf = (lane < 32);

  for (int it = 0; it < 64; it++) {
    __syncthreads();
    if (it + 1 < 64) {
      const int nb = (it + 1) & 1, kv0 = (it + 1) * 32;
      const int kr = tid >> 3, sl = tid & 7;
      lds_cp16(smc + nb * 4096 + tid * 16,
               kb8 + kbase8 + (size_t)(kv0 + kr) * 1024 + (sl ^ (kr & 7)) * 16);
      lds_cp16(smc + 8192 + nb * 4096 + tid * 16,
               vt8 + vbase8 + (size_t)kv0 * 128 + (tid >> 6) * 1024 + (tid & 63) * 16);
    }
    const int cur = it & 1;

    // S^T = K Q^T in fp8 (granule-paired; 4 b128 reads, 16 MFMA)
    floatx4 st[2][2];  // [kv-16-tile mt][q-tile nt]
#pragma unroll
    for (int mt = 0; mt < 2; mt++)
#pragma unroll
      for (int nt = 0; nt < 2; nt++) { floatx4 z = {0.f, 0.f, 0.f, 0.f}; st[mt][nt] = z; }
    __builtin_amdgcn_s_setprio(1);
#pragma unroll
    for (int p = 0; p < 2; p++) {
#pragma unroll
      for (int mt = 0; mt < 2; mt++) {
        const longx2 kk = *(const longx2*)(smc + cur * 4096 + (mt * 16 + l16) * 128 +
                                           (((p * 4 + qd) ^ (l16 & 7)) << 4));
        st[mt][0] = __builtin_amdgcn_mfma_f32_16x16x32_fp8_fp8(kk.x, qx[p][0], st[mt][0], 0, 0, 0);
        st[mt][1] = __builtin_amdgcn_mfma_f32_16x16x32_fp8_fp8(kk.x, qx[p][1], st[mt][1], 0, 0, 0);
        st[mt][0] = __builtin_amdgcn_mfma_f32_16x16x32_fp8_fp8(kk.y, qy[p][0], st[mt][0], 0, 0, 0);
        st[mt][1] = __builtin_amdgcn_mfma_f32_16x16x32_fp8_fp8(kk.y, qy[p][1], st[mt][1], 0, 0, 0);
      }
    }
    __builtin_amdgcn_s_setprio(0);

    // hoist V^T A-frags (fp8, 8B each) — latency hides under the exp VALU
    long vl[8];
#pragma unroll
    for (int mt = 0; mt < 8; mt++)
      vl[mt] = *(const long*)(smc + 8192 + cur * 4096 + qd * 1024 + (mt * 16 + l16) * 8);

    // P = exp(S^T/32): pack 4 fp8 per u32 (one kv-quad), per-lane row-sums
    uint32_t pkf[2][2];
#pragma unroll
    for (int mt = 0; mt < 2; mt++)
#pragma unroll
      for (int nt = 0; nt < 2; nt++) {
        const float e0 = __expf(st[mt][nt][0] * 0.03125f);
        const float e1 = __expf(st[mt][nt][1] * 0.03125f);
        const float e2 = __expf(st[mt][nt][2] * 0.03125f);
        const float e3 = __expf(st[mt][nt][3] * 0.03125f);
        lsum[nt] += (e0 + e1) + (e2 + e3);
        int p = __builtin_amdgcn_cvt_pk_fp8_f32(e0, e1, 0, false);
        p = __builtin_amdgcn_cvt_pk_fp8_f32(e2, e3, p, true);
        pkf[mt][nt] = (uint32_t)p;
      }

    // Assemble P^T fp8 B-frags via quad redistribution (4 bpermute/nt),
    // then O^T += V^T P^T in fp8
#pragma unroll
    for (int nt = 0; nt < 2; nt++) {
      int lo0 = __builtin_amdgcn_ds_bpermute(addrLo, (int)pkf[0][nt]);
      int lo1 = __builtin_amdgcn_ds_bpermute(addrLo, (int)pkf[1][nt]);
      int hi0 = __builtin_amdgcn_ds_bpermute(addrHi, (int)pkf[0][nt]);
      int hi1 = __builtin_amdgcn_ds_bpermute(addrHi, (int)pkf[1][nt]);
      union { int i[2]; long l; } u;
      u.i[0] = loHalf ? lo0 : lo1;
      u.i[1] = loHalf ? hi0 : hi1;
      const long pfl = u.l;
      __builtin_amdgcn_s_setprio(1);
#pragma unroll
      for (int mt = 0; mt < 8; mt++)
        oacc[mt][nt] =
            __builtin_amdgcn_mfma_f32_16x16x32_fp8_fp8(vl[mt], pfl, oacc[mt][nt], 0, 0, 0);
      __builtin_amdgcn_s_setprio(0);
    }
  }

  // finalize row sums (reduce over quads; q lives in l16)
  float inv[2];
#pragma unroll
  for (int nt = 0; nt < 2; nt++) {
    float s = lsum[nt];
    s += __shfl_xor(s, 16);
    s += __shfl_xor(s, 32);
    inv[nt] = 1.f / s;
  }

  // ---- transpose O^T back via XOR-swizzled LDS, add residual, store ----
  __syncthreads();  // all K/V reads done; smem reusable
#pragma unroll
  for (int mt = 0; mt < 8; mt++)
#pragma unroll
    for (int nt = 0; nt < 2; nt++) {
      const int q = w * 32 + nt * 16 + l16;
#pragma unroll
      for (int r = 0; r < 4; r++) {
        const int dh = mt * 16 + qd * 4 + r;
        const int c = dh >> 3, off = dh & 7;
        sm16[q * 128 + ((c ^ (q & 15)) * 8) + off] = f2bf_trunc(oacc[mt][nt][r] * inv[nt]);
      }
    }
  __syncthreads();
#pragma unroll
  for (int i = 0; i < 8; i++) {
    const int p = i * 256 + tid;
    const int row = p >> 4, c = p & 15;
    const short8 ov = *(const short8*)&sm16[row * 128 + ((c ^ (row & 15)) * 8)];
    const short8 qres = *(const short8*)(qb + qbase + (size_t)row * 1024 + c * 8);
    union { unsigned short us[8]; short8 s; } o;
#pragma unroll
    for (int e = 0; e < 8; e++)
      o.us[e] = f2bf(bf2f((unsigned short)ov[e]) + bf2f((unsigned short)qres[e]));
    *(short8*)(Ob + qbase + (size_t)row * 1024 + c * 8) = o.s;
  }
}

// =====================================================================
// Row LayerNorm over 1024 (bf16 -> bf16)
// =====================================================================
__global__ __launch_bounds__(256) void ln_rows(const unsigned short* __restrict__ X,
                                               const float* __restrict__ g,
                                               const float* __restrict__ bb,
                                               unsigned short* __restrict__ Y) {
  __shared__ float red[8];
  const int row = blockIdx.x, tid = threadIdx.x;
  const int w = tid >> 6, lane = tid & 63;
  const ushortx4 u = ((const ushortx4*)(X + (size_t)row * 1024))[tid];
  float x0 = bf2f(u.x), x1 = bf2f(u.y), x2 = bf2f(u.z), x3 = bf2f(u.w);
  float s = x0 + x1 + x2 + x3;
  float s2 = x0 * x0 + x1 * x1 + x2 * x2 + x3 * x3;
#pragma unroll
  for (int off = 1; off < 64; off <<= 1) { s += __shfl_xor(s, off); s2 += __shfl_xor(s2, off); }
  if (lane == 0) { red[w] = s; red[4 + w] = s2; }
  __syncthreads();
  s = red[0] + red[1] + red[2] + red[3];
  s2 = red[4] + red[5] + red[6] + red[7];
  const float mu = s * (1.f / 1024.f);
  const float rs = rsqrtf(s2 * (1.f / 1024.f) - mu * mu + 1e-5f);
  const floatx4 gv = ((const floatx4*)g)[tid];
  const floatx4 bv = ((const floatx4*)bb)[tid];
  ushortx4 o;
  o.x = f2bf((x0 - mu) * rs * gv.x + bv.x);
  o.y = f2bf((x1 - mu) * rs * gv.y + bv.y);
  o.z = f2bf((x2 - mu) * rs * gv.z + bv.z);
  o.w = f2bf((x3 - mu) * rs * gv.w + bv.w);
  ((ushortx4*)(Y + (size_t)row * 1024))[tid] = o;
}

// =====================================================================
// Row LayerNorm over 1024 (bf16 -> f32) for the final output
// =====================================================================
__global__ __launch_bounds__(256) void ln_b2f(const unsigned short* __restrict__ X,
                                              const float* __restrict__ g,
                                              const float* __restrict__ bb,
                                              float* __restrict__ out) {
  __shared__ float red[8];
  const int row = blockIdx.x, tid = threadIdx.x;
  const int w = tid >> 6, lane = tid & 63;
  const ushortx4 u = ((const ushortx4*)(X + (size_t)row * 1024))[tid];
  float x0 = bf2f(u.x), x1 = bf2f(u.y), x2 = bf2f(u.z), x3 = bf2f(u.w);
  float s = x0 + x1 + x2 + x3;
  float s2 = x0 * x0 + x1 * x1 + x2 * x2 + x3 * x3;
#pragma unroll
  for (int off = 1; off < 64; off <<= 1) { s += __shfl_xor(s, off); s2 += __shfl_xor(s2, off); }
  if (lane == 0) { red[w] = s; red[4 + w] = s2; }
  __syncthreads();
  s = red[0] + red[1] + red[2] + red[3];
  s2 = red[4] + red[5] + red[6] + red[7];
  const float mu = s * (1.f / 1024.f);
  const float rs = rsqrtf(s2 * (1.f / 1024.f) - mu * mu + 1e-5f);
  const floatx4 gv = ((const floatx4*)g)[tid];
  const floatx4 bv = ((const floatx4*)bb)[tid];
  floatx4 o;
  o.x = (x0 - mu) * rs * gv.x + bv.x;
  o.y = (x1 - mu) * rs * gv.y + bv.y;
  o.z = (x2 - mu) * rs * gv.z + bv.z;
  o.w = (x3 - mu) * rs * gv.w + bv.w;
  ((floatx4*)(out + (size_t)row * 1024))[tid] = o;
}

// =====================================================================
// Host launch
// =====================================================================
extern "C" void kernel_launch(void* const* d_in, const int* in_sizes, int n_in,
                              void* d_out, int out_size, void* d_ws, size_t ws_size,
                              hipStream_t stream) {
  (void)in_sizes; (void)n_in; (void)out_size; (void)ws_size;
  const float* Q  = (const float*)d_in[0];
  const float* K  = (const float*)d_in[1];
  const float* Wq = (const float*)d_in[2];
  const float* bq = (const float*)d_in[3];
  const float* Wk = (const float*)d_in[4];
  const float* bk = (const float*)d_in[5];
  const float* Wv = (const float*)d_in[6];
  const float* bv = (const float*)d_in[7];
  const float* Wo = (const float*)d_in[8];
  const float* bo = (const float*)d_in[9];
  const float* g0 = (const float*)d_in[10];
  const float* b0 = (const float*)d_in[11];
  const float* g1 = (const float*)d_in[12];
  const float* b1 = (const float*)d_in[13];
  float* out = (float*)d_out;

  char* ws = (char*)d_ws;
  const size_t MB = 1u << 20;
  unsigned short* Qb  = (unsigned short*)(ws + 0);         // 16 MB [later: O bf16]
  unsigned short* X1  = (unsigned short*)(ws + 16 * MB);   // 16 MB
  unsigned short* Wt  = (unsigned short*)(ws + 32 * MB);   // 4 MB bf16 [Wq^T;Wo^T]
  unsigned char*  Wt8 = (unsigned char*)(ws + 36 * MB);    // 2 MB fp8 [Wk^T;Wv^T]
  unsigned char*  Kf8 = (unsigned char*)(ws + 38 * MB);    // 16 MB
  unsigned short* qbp = (unsigned short*)(ws + 54 * MB);   // 16 MB
  unsigned char*  kb8p = (unsigned char*)(ws + 70 * MB);   // 16 MB fp8 K [later: O2 bf16]
  unsigned char*  vt8 = (unsigned char*)(ws + 102 * MB);   // 16 MB fp8 V
  unsigned short* O   = Qb;
  unsigned short* O2b = (unsigned short*)(ws + 70 * MB);

  unsigned short* Wqt = Wt;
  unsigned short* Wot = Wt + (size_t)1024 * 1024;

  cvt_qk<<<24576, 256, 0, stream>>>(Q, K, Qb, Kf8);
  wtrans4<<<dim3(32, 32, 4), dim3(32, 8), 0, stream>>>(Wq, Wk, Wv, Wo, Wt, Wt8);

  // Q projection -> qbp (bf16 rowmajor), 128x128 bf16, XCD m-banded
  gemm_bt<0><<<512, 256, 0, stream>>>(Qb, Wqt, bq, nullptr, qbp);
  // fused K+V projection in FP8 (M=16384, N=2048); K out fp8, V out fp8
  gemm_kv_f8<<<2048, 256, 0, stream>>>(Kf8, Wt8, bk, bv, kb8p, vt8);
  // attention (+ q residual) -> O bf16; QK fp8, PV fp8, KVBLK=32
  attn<<<512, 256, 0, stream>>>(qbp, kb8p, vt8, O);
  // LN0
  ln_rows<<<8192, 256, 0, stream>>>(O, g0, b0, X1);
  // O2 = bf16(X1 + relu(X1 @ Wo + bo)), XCD m-banded
  gemm_bt<2><<<512, 256, 0, stream>>>(X1, Wot, bo, X1, O2b);
  // out = LN(O2)
  ln_b2f<<<8192, 256, 0, stream>>>(O2b, g1, b1, out);
}